// Round 3
// baseline (447.034 us; speedup 1.0000x reference)
//
#include <hip/hip_runtime.h>
#include <math.h>

#define N_EXP 64
#define TOPK 8
#define TOPK_G 4
#define D_DIM 2048
#define BM 64
#define WAVES 16
#define THREADS 1024
#define KW (D_DIM / WAVES)   // 128 k per wave
#define BK 8                 // k per staged chunk
#define NCHUNK (KW / BK)     // 16

// LDS map (floats), 32768 total = 128 KB:
//   GEMM phase : wave w staging at [w*2048]; double buffer p at +p*1024;
//                x chunk [BK][64] at +0, W chunk [BK][64] at +512
//   Reduce     : part[2][64][64] at [p*4096] (reuses staging region)
//   Final      : sc[64][65] at [8192], bias at [12352]
__launch_bounds__(THREADS, 4)
__global__ void router_kernel(const float* __restrict__ x,
                              const float* __restrict__ W,
                              const float* __restrict__ bias,
                              float* __restrict__ out_idx,
                              float* __restrict__ out_w)
{
    __shared__ float smem[32768];

    const int tid  = threadIdx.x;
    const int wave = tid >> 6;
    const int lane = tid & 63;
    const int lm   = lane >> 3;   // thread rows  = lm*8 + i
    const int ln   = lane & 7;    // thread exps  = ln*8 + j
    const int row0 = blockIdx.x * BM;
    const int base = wave * 2048;

    const float* xrow = x + (size_t)(row0 + lane) * D_DIM + wave * KW;
    const float* wrow = W + (size_t)lane * D_DIM + wave * KW;

    float acc[8][8];
#pragma unroll
    for (int i = 0; i < 8; ++i)
#pragma unroll
        for (int j = 0; j < 8; ++j) acc[i][j] = 0.f;

    float4 gx0, gx1, gw0, gw1;

#define LOADG(c)  do { \
        const float* xp = xrow + (c) * BK; \
        const float* wp = wrow + (c) * BK; \
        gx0 = *(const float4*)(xp);     gx1 = *(const float4*)(xp + 4); \
        gw0 = *(const float4*)(wp);     gw1 = *(const float4*)(wp + 4); \
    } while (0)

#define STOREG(off) do { \
        smem[(off) + 0 * 64 + lane] = gx0.x; smem[(off) + 1 * 64 + lane] = gx0.y; \
        smem[(off) + 2 * 64 + lane] = gx0.z; smem[(off) + 3 * 64 + lane] = gx0.w; \
        smem[(off) + 4 * 64 + lane] = gx1.x; smem[(off) + 5 * 64 + lane] = gx1.y; \
        smem[(off) + 6 * 64 + lane] = gx1.z; smem[(off) + 7 * 64 + lane] = gx1.w; \
        smem[(off) + 512 + 0 * 64 + lane] = gw0.x; smem[(off) + 512 + 1 * 64 + lane] = gw0.y; \
        smem[(off) + 512 + 2 * 64 + lane] = gw0.z; smem[(off) + 512 + 3 * 64 + lane] = gw0.w; \
        smem[(off) + 512 + 4 * 64 + lane] = gw1.x; smem[(off) + 512 + 5 * 64 + lane] = gw1.y; \
        smem[(off) + 512 + 6 * 64 + lane] = gw1.z; smem[(off) + 512 + 7 * 64 + lane] = gw1.w; \
    } while (0)

    // prologue: chunk 0 -> buf0; chunk 1 -> regs
    LOADG(0);
    STOREG(base);
    LOADG(1);

    for (int c = 0; c < NCHUNK; ++c) {
        // 1) write chunk c+1 (regs loaded one iter ago) into the other buffer
        if (c + 1 < NCHUNK) STOREG(base + ((c + 1) & 1) * 1024);
        // 2) issue global loads for chunk c+2 (latency hidden under compute)
        if (c + 2 < NCHUNK) LOADG(c + 2);
        // 3) compute chunk c
        const int cb = base + (c & 1) * 1024;
#pragma unroll
        for (int k = 0; k < BK; ++k) {
            float fx[8], fw[8];
            *(float4*)&fx[0] = *(const float4*)&smem[cb + k * 64 + lm * 8];
            *(float4*)&fx[4] = *(const float4*)&smem[cb + k * 64 + lm * 8 + 4];
            *(float4*)&fw[0] = *(const float4*)&smem[cb + 512 + k * 64 + ln * 8];
            *(float4*)&fw[4] = *(const float4*)&smem[cb + 512 + k * 64 + ln * 8 + 4];
#pragma unroll
            for (int i = 0; i < 8; ++i)
#pragma unroll
                for (int j = 0; j < 8; ++j)
                    acc[i][j] = fmaf(fx[i], fw[j], acc[i][j]);
        }
    }
#undef LOADG
#undef STOREG

    // ---- cross-wave k-reduction: 8 rounds of 2 waves into part[2][64][64] ----
    float red[4] = {0.f, 0.f, 0.f, 0.f};
    const int r2 = tid >> 4;          // reduction row 0..63
    const int eq = (tid & 15) * 4;    // reduction expert quad base
    const int rsw = 4 * (r2 >> 3);    // reader swizzle

    __syncthreads(); // all GEMM LDS traffic done before region reuse
    if (tid < N_EXP) smem[12352 + tid] = bias[tid];

    for (int rj = 0; rj < 8; ++rj) {
        if (rj) __syncthreads(); // prior round's reads done
        if ((wave >> 1) == rj) {
            const int p = wave & 1;
#pragma unroll
            for (int i = 0; i < 8; ++i) {
                const int r = lm * 8 + i;
#pragma unroll
                for (int q = 0; q < 2; ++q) {
                    const int ec = (ln * 8 + q * 4 + 4 * lm) & 63; // writer swizzle
                    *(float4*)&smem[p * 4096 + r * 64 + ec] =
                        make_float4(acc[i][q * 4 + 0], acc[i][q * 4 + 1],
                                    acc[i][q * 4 + 2], acc[i][q * 4 + 3]);
                }
            }
        }
        __syncthreads();
#pragma unroll
        for (int p = 0; p < 2; ++p) {
            const int ec = (eq + rsw) & 63;
            const float4 v = *(const float4*)&smem[p * 4096 + r2 * 64 + ec];
            red[0] += v.x; red[1] += v.y; red[2] += v.z; red[3] += v.w;
        }
    }

    // sigmoid in registers, scatter to sc[64][65] (pitch 65: conflict-free rows)
    {
#pragma unroll
        for (int t = 0; t < 4; ++t)
            smem[8192 + r2 * 65 + eq + t] = 1.0f / (1.0f + expf(-red[t]));
    }
    __syncthreads();

    // ---- selection: thread r handles row r ----
    if (tid < BM) {
        const int r = tid;
        float gmax[8];
#pragma unroll
        for (int g = 0; g < 8; ++g) {
            float m = -INFINITY;
#pragma unroll
            for (int j = 0; j < 8; ++j) {
                float v = smem[8192 + r * 65 + g * 8 + j] + smem[12352 + g * 8 + j];
                m = fmaxf(m, v);
            }
            gmax[g] = m;
        }
        unsigned gsel = 0;
        for (int k = 0; k < TOPK_G; ++k) {
            int best = 0; float bv = -INFINITY;
#pragma unroll
            for (int g = 0; g < 8; ++g)
                if (!((gsel >> g) & 1) && gmax[g] > bv) { bv = gmax[g]; best = g; }
            gsel |= 1u << best;
        }
        unsigned long long emask = 0ull;
#pragma unroll
        for (int g = 0; g < 8; ++g)
            if ((gsel >> g) & 1) emask |= (0xFFull << (g * 8));

        const int grow = row0 + r;
        unsigned long long esel = 0ull;
        float wsum = 0.f;
        for (int k = 0; k < TOPK; ++k) {
            int best = 0; float bv = -INFINITY;
            for (int e = 0; e < N_EXP; ++e) {
                if (((emask >> e) & 1) && !((esel >> e) & 1)) {
                    float v = smem[8192 + r * 65 + e] + smem[12352 + e];
                    if (v > bv) { bv = v; best = e; }
                }
            }
            esel |= 1ull << best;
            const float w8 = smem[8192 + r * 65 + best];
            out_idx[grow * TOPK + k] = (float)best;
            out_w[grow * TOPK + k]  = w8;
            wsum += w8;
        }
        const float inv = 1.0f / (wsum + 1e-20f);
        for (int k = 0; k < TOPK; ++k)
            out_w[grow * TOPK + k] *= inv;
    }
}

extern "C" void kernel_launch(void* const* d_in, const int* in_sizes, int n_in,
                              void* d_out, int out_size, void* d_ws, size_t ws_size,
                              hipStream_t stream) {
    const float* x    = (const float*)d_in[0];
    const float* W    = (const float*)d_in[1];
    const float* bias = (const float*)d_in[2];
    float* out = (float*)d_out;

    const int n_wg = 16384 / BM; // 256 WGs -> 1 per CU, 16 waves each
    hipLaunchKernelGGL(router_kernel, dim3(n_wg), dim3(THREADS), 0, stream,
                       x, W, bias, out, out + 16384 * TOPK);
}

// Round 4
// 121.431 us; speedup vs baseline: 3.6814x; 3.6814x over previous
//
#include <hip/hip_runtime.h>
#include <math.h>

#define N_EXP 64
#define TOPK 8
#define TOPK_G 4
#define D_DIM 2048
#define BM 64
#define WAVES 8
#define THREADS 512
#define KHALF 1024           // k per workgroup (2-way k-split across WGs)
#define KW (KHALF / WAVES)   // 128 k per wave
#define BK 8                 // k per staged chunk
#define NCHUNK (KW / BK)     // 16
#define S_TOT 16384

// ---------------- kernel 1: GEMM partial (one k-half per WG) ----------------
// grid 512 = 256 row-blocks x 2 k-halves; 512 thr (8 waves); ~120 VGPR ->
// 4 waves/SIMD, 2 blocks/CU. LDS 64 KB: wave w staging at [w*2048],
// double buffer p at +p*1024 (x chunk [BK][64] at +0, W chunk [BK][64] at +512).
// Reduction overlays part[2][64][64] at [0].
__launch_bounds__(THREADS)
__global__ void gemm_half_kernel(const float* __restrict__ x,
                                 const float* __restrict__ W,
                                 float* __restrict__ part)
{
    __shared__ float smem[16384];

    const int tid  = threadIdx.x;
    const int wave = tid >> 6;
    const int lane = tid & 63;
    const int lm   = lane >> 3;   // thread rows = lm*8 + i
    const int ln   = lane & 7;    // thread exps = ln*8 + j
    const int rb   = blockIdx.x >> 1;
    const int kh   = blockIdx.x & 1;
    const int row0 = rb * BM;
    const int base = wave * 2048;

    const float* xrow = x + (size_t)(row0 + lane) * D_DIM + kh * KHALF + wave * KW;
    const float* wrow = W + (size_t)lane * D_DIM + kh * KHALF + wave * KW;

    float acc[8][8];
#pragma unroll
    for (int i = 0; i < 8; ++i)
#pragma unroll
        for (int j = 0; j < 8; ++j) acc[i][j] = 0.f;

    float4 gx0, gx1, gw0, gw1;

#define LOADG(c)  do { \
        const float* xp = xrow + (c) * BK; \
        const float* wp = wrow + (c) * BK; \
        gx0 = *(const float4*)(xp);     gx1 = *(const float4*)(xp + 4); \
        gw0 = *(const float4*)(wp);     gw1 = *(const float4*)(wp + 4); \
    } while (0)

#define STOREG(off) do { \
        smem[(off) + 0 * 64 + lane] = gx0.x; smem[(off) + 1 * 64 + lane] = gx0.y; \
        smem[(off) + 2 * 64 + lane] = gx0.z; smem[(off) + 3 * 64 + lane] = gx0.w; \
        smem[(off) + 4 * 64 + lane] = gx1.x; smem[(off) + 5 * 64 + lane] = gx1.y; \
        smem[(off) + 6 * 64 + lane] = gx1.z; smem[(off) + 7 * 64 + lane] = gx1.w; \
        smem[(off) + 512 + 0 * 64 + lane] = gw0.x; smem[(off) + 512 + 1 * 64 + lane] = gw0.y; \
        smem[(off) + 512 + 2 * 64 + lane] = gw0.z; smem[(off) + 512 + 3 * 64 + lane] = gw0.w; \
        smem[(off) + 512 + 4 * 64 + lane] = gw1.x; smem[(off) + 512 + 5 * 64 + lane] = gw1.y; \
        smem[(off) + 512 + 6 * 64 + lane] = gw1.z; smem[(off) + 512 + 7 * 64 + lane] = gw1.w; \
    } while (0)

    // prologue: chunk 0 -> buf0; chunk 1 -> regs
    LOADG(0);
    STOREG(base);
    LOADG(1);

    for (int c = 0; c < NCHUNK; ++c) {
        if (c + 1 < NCHUNK) STOREG(base + ((c + 1) & 1) * 1024);
        if (c + 2 < NCHUNK) LOADG(c + 2);
        const int cb = base + (c & 1) * 1024;
#pragma unroll
        for (int k = 0; k < BK; ++k) {
            float fx[8], fw[8];
            *(float4*)&fx[0] = *(const float4*)&smem[cb + k * 64 + lm * 8];
            *(float4*)&fx[4] = *(const float4*)&smem[cb + k * 64 + lm * 8 + 4];
            *(float4*)&fw[0] = *(const float4*)&smem[cb + 512 + k * 64 + ln * 8];
            *(float4*)&fw[4] = *(const float4*)&smem[cb + 512 + k * 64 + ln * 8 + 4];
#pragma unroll
            for (int i = 0; i < 8; ++i)
#pragma unroll
                for (int j = 0; j < 8; ++j)
                    acc[i][j] = fmaf(fx[i], fw[j], acc[i][j]);
        }
    }
#undef LOADG
#undef STOREG

    // cross-wave k-reduction: 4 rounds of 2 waves into part[2][64][64] overlay
    float red[8];
#pragma unroll
    for (int j = 0; j < 8; ++j) red[j] = 0.f;
    const int r2 = tid >> 3;          // 0..63
    const int e0 = (tid & 7) * 8;
    const int rsw = 4 * (r2 >> 3);

    for (int rj = 0; rj < 4; ++rj) {
        __syncthreads(); // rj=0: GEMM LDS reads done; else prior round reads done
        if ((wave >> 1) == rj) {
            const int p = wave & 1;
#pragma unroll
            for (int i = 0; i < 8; ++i) {
                const int r = lm * 8 + i;
#pragma unroll
                for (int q = 0; q < 2; ++q) {
                    const int ec = (ln * 8 + q * 4 + 4 * lm) & 63; // writer swizzle
                    *(float4*)&smem[p * 4096 + r * 64 + ec] =
                        make_float4(acc[i][q * 4 + 0], acc[i][q * 4 + 1],
                                    acc[i][q * 4 + 2], acc[i][q * 4 + 3]);
                }
            }
        }
        __syncthreads();
#pragma unroll
        for (int p = 0; p < 2; ++p) {
#pragma unroll
            for (int q = 0; q < 2; ++q) {
                const int ec = (e0 + q * 4 + rsw) & 63;
                const float4 v = *(const float4*)&smem[p * 4096 + r2 * 64 + ec];
                red[q * 4 + 0] += v.x; red[q * 4 + 1] += v.y;
                red[q * 4 + 2] += v.z; red[q * 4 + 3] += v.w;
            }
        }
    }

    // store partial logits: ws[kh][row0+r2][e0..e0+8), coalesced float4 x2
    float* dst = part + ((size_t)kh * S_TOT + row0 + r2) * N_EXP + e0;
    *(float4*)(dst)     = make_float4(red[0], red[1], red[2], red[3]);
    *(float4*)(dst + 4) = make_float4(red[4], red[5], red[6], red[7]);
}

// ---------------- kernel 2: sum halves + sigmoid + grouped top-k ----------------
__global__ void select_kernel(const float* __restrict__ part,
                              const float* __restrict__ bias,
                              float* __restrict__ out_idx,
                              float* __restrict__ out_w)
{
    __shared__ float sc[64 * 65];
    __shared__ float bias_s[64];

    const int lane = threadIdx.x;            // 64 threads, 1 wave
    const int row  = blockIdx.x * 64 + lane;
    bias_s[lane] = bias[lane];

    const float* p0 = part + (size_t)row * N_EXP;
    const float* p1 = part + ((size_t)S_TOT + row) * N_EXP;
#pragma unroll
    for (int q = 0; q < 16; ++q) {
        float4 a = *(const float4*)(p0 + q * 4);
        float4 b = *(const float4*)(p1 + q * 4);
        sc[lane * 65 + q * 4 + 0] = 1.0f / (1.0f + expf(-(a.x + b.x)));
        sc[lane * 65 + q * 4 + 1] = 1.0f / (1.0f + expf(-(a.y + b.y)));
        sc[lane * 65 + q * 4 + 2] = 1.0f / (1.0f + expf(-(a.z + b.z)));
        sc[lane * 65 + q * 4 + 3] = 1.0f / (1.0f + expf(-(a.w + b.w)));
    }
    __syncthreads(); // bias_s visibility

    const int r = lane;
    float gmax[8];
#pragma unroll
    for (int g = 0; g < 8; ++g) {
        float m = -INFINITY;
#pragma unroll
        for (int j = 0; j < 8; ++j) {
            float v = sc[r * 65 + g * 8 + j] + bias_s[g * 8 + j];
            m = fmaxf(m, v);
        }
        gmax[g] = m;
    }
    unsigned gsel = 0;
    for (int k = 0; k < TOPK_G; ++k) {
        int best = 0; float bv = -INFINITY;
#pragma unroll
        for (int g = 0; g < 8; ++g)
            if (!((gsel >> g) & 1) && gmax[g] > bv) { bv = gmax[g]; best = g; }
        gsel |= 1u << best;
    }
    unsigned long long emask = 0ull;
#pragma unroll
    for (int g = 0; g < 8; ++g)
        if ((gsel >> g) & 1) emask |= (0xFFull << (g * 8));

    unsigned long long esel = 0ull;
    float wsum = 0.f;
    float wv[TOPK]; int iv[TOPK];
    for (int k = 0; k < TOPK; ++k) {
        int best = 0; float bv = -INFINITY;
        for (int e = 0; e < N_EXP; ++e) {
            if (((emask >> e) & 1) && !((esel >> e) & 1)) {
                float v = sc[r * 65 + e] + bias_s[e];
                if (v > bv) { bv = v; best = e; }
            }
        }
        esel |= 1ull << best;
        iv[k] = best;
        wv[k] = sc[r * 65 + best];
        wsum += wv[k];
    }
    const float inv = 1.0f / (wsum + 1e-20f);
#pragma unroll
    for (int k = 0; k < TOPK; ++k) {
        out_idx[row * TOPK + k] = (float)iv[k];
        out_w[row * TOPK + k]   = wv[k] * inv;
    }
}

extern "C" void kernel_launch(void* const* d_in, const int* in_sizes, int n_in,
                              void* d_out, int out_size, void* d_ws, size_t ws_size,
                              hipStream_t stream) {
    const float* x    = (const float*)d_in[0];
    const float* W    = (const float*)d_in[1];
    const float* bias = (const float*)d_in[2];
    float* out  = (float*)d_out;
    float* part = (float*)d_ws; // needs 2*16384*64*4 = 8 MB scratch

    hipLaunchKernelGGL(gemm_half_kernel, dim3((S_TOT / BM) * 2), dim3(THREADS), 0, stream,
                       x, W, part);
    hipLaunchKernelGGL(select_kernel, dim3(S_TOT / 64), dim3(64), 0, stream,
                       part, bias, out, out + S_TOT * TOPK);
}